// Round 1
// baseline (112.253 us; speedup 1.0000x reference)
//
#include <hip/hip_runtime.h>

// RelativePositionalEncoding2D: out[b,i,j,e] = W[e, pos] + bias[e]
//   pos = clip(idxs[b,j] - idxs[b,i], -32, 32) + 32
// Shapes: B=1, S=1024, E=128, N=65. Output fp32 (1,S,S,E) = 512 MiB -> pure
// HBM-write-bound. Strategy: precompute table[pos][e] = W[e,pos]+bias[e] in
// LDS (33 KB) per block, then stream coalesced float4 stores.

#define MAXGAP 32
#define NIDX   65     // 2*MAXGAP+1
#define EDIM   128
#define E4     32     // EDIM/4 float4 per output row

__global__ __launch_bounds__(256) void relpos2d_kernel(
    const int* __restrict__ idxs,
    const float* __restrict__ W,       // (E, N) row-major
    const float* __restrict__ bias,    // (E,)
    float4* __restrict__ out,          // (B*S*S, E4)
    int S, int SS, int rows_total)
{
    __shared__ float table[NIDX][EDIM];   // 65*128*4 = 33,280 B

    // Fill table[p][e] = W[e*N + p] + bias[e]; 8320 elems / 256 thr = 33 iters.
    for (int t = threadIdx.x; t < NIDX * EDIM; t += 256) {
        int p = t >> 7;          // t / 128
        int e = t & 127;         // t % 128
        table[p][e] = W[e * NIDX + p] + bias[e];
    }
    __syncthreads();

    const int lane4 = threadIdx.x & 31;   // which float4 within the row
    const int rsub  = threadIdx.x >> 5;   // 0..7: row within this block-step
    const int ROWS_PER_STEP = 256 / 32;   // 8 rows per block per step

    for (int row = blockIdx.x * ROWS_PER_STEP + rsub; row < rows_total;
         row += gridDim.x * ROWS_PER_STEP) {
        // row -> (b, i, j)
        int bi  = row / SS;
        int rem = row - bi * SS;
        int i   = rem / S;
        int j   = rem - i * S;

        int d = idxs[bi * S + j] - idxs[bi * S + i];
        d = d < -MAXGAP ? -MAXGAP : (d > MAXGAP ? MAXGAP : d);
        int p = d + MAXGAP;

        const float4* trow = reinterpret_cast<const float4*>(&table[p][0]);
        out[(size_t)row * E4 + lane4] = trow[lane4];
    }
}

extern "C" void kernel_launch(void* const* d_in, const int* in_sizes, int n_in,
                              void* d_out, int out_size, void* d_ws, size_t ws_size,
                              hipStream_t stream) {
    const int*   idxs = (const int*)  d_in[0];   // (B*S,) int32
    const float* W    = (const float*)d_in[1];   // (E, N) fp32
    const float* bias = (const float*)d_in[2];   // (E,)  fp32

    float* out = (float*)d_out;

    const int S  = in_sizes[0];   // B = 1 per setup_inputs (idxs flat = B*S)
    const int SS = S * S;
    const int rows_total = SS;    // B*S*S with B=1

    const int grid = 2048;        // 256 CU x 8 blocks; grid-stride covers rest
    relpos2d_kernel<<<grid, 256, 0, stream>>>(
        idxs, W, bias, (float4*)out, S, SS, rows_total);
}

// Round 3
// 103.552 us; speedup vs baseline: 1.0840x; 1.0840x over previous
//
#include <hip/hip_runtime.h>

// RelativePositionalEncoding2D: out[b,i,j,e] = W[e, pos] + bias[e]
//   pos = clip(idxs[b,j] - idxs[b,i], -32, 32) + 32
// Shapes: B=1, S=1024, E=128, N=65. Output fp32 (1,S,S,E) = 512 MiB -> pure
// HBM-write-bound (floor ~78us at 6.8 TB/s measured fill BW).
//
// R2 -> R3: fix compile error only. __builtin_nontemporal_store requires a
// clang vector type, not HIP's float4 struct -> use ext_vector_type(4).
//
// Structure (unchanged from R2 theory):
//  - block -> (i, half-row) tile directly: no integer divides anywhere
//  - idxs[i] hoisted to a register; block's idxs[j] slice staged in LDS
//  - #pragma unroll 4 on j-loop: 4 independent ds_read->store in flight
//  - nontemporal stores (output has zero reuse, don't thrash L2/L3)

#define MAXGAP 32
#define NIDX   65     // 2*MAXGAP+1
#define EDIM   128
#define E4     32     // EDIM/4 float4 per output row
#define CHUNKS 2      // half-rows per i

typedef float f32x4 __attribute__((ext_vector_type(4)));

__global__ __launch_bounds__(256) void relpos2d_kernel(
    const int* __restrict__ idxs,
    const float* __restrict__ W,       // (E, N) row-major
    const float* __restrict__ bias,    // (E,)
    f32x4* __restrict__ out,           // (S*S, E4)
    int S, int halfS)
{
    __shared__ float table[NIDX][EDIM];   // 33,280 B
    __shared__ int   jidx[1024];          // up to halfS entries used

    // table[p][e] = W[e*N + p] + bias[e]
    for (int t = threadIdx.x; t < NIDX * EDIM; t += 256) {
        int p = t >> 7;
        int e = t & 127;
        table[p][e] = W[e * NIDX + p] + bias[e];
    }

    const int i     = blockIdx.x >> 1;       // CHUNKS == 2
    const int chunk = blockIdx.x & (CHUNKS - 1);
    const int jbase = chunk * halfS;

    // stage this block's idxs[j] slice
    for (int t = threadIdx.x; t < halfS; t += 256)
        jidx[t] = idxs[jbase + t];

    __syncthreads();

    const int lane4 = threadIdx.x & 31;   // float4 slot within the 512B row
    const int jsub  = threadIdx.x >> 5;   // 0..7: j within this step
    const int idx_i = idxs[i];

    f32x4* __restrict__ orow = out + (size_t)i * S * E4 + (size_t)jbase * E4;

    #pragma unroll 4
    for (int jj = 0; jj < halfS; jj += 8) {
        int j = jj + jsub;
        int d = jidx[j] - idx_i;                       // LDS broadcast read
        d = d < -MAXGAP ? -MAXGAP : (d > MAXGAP ? MAXGAP : d);
        int p = d + MAXGAP;

        f32x4 v = reinterpret_cast<const f32x4*>(&table[p][0])[lane4];
        __builtin_nontemporal_store(v, &orow[(size_t)j * E4 + lane4]);
    }
}

extern "C" void kernel_launch(void* const* d_in, const int* in_sizes, int n_in,
                              void* d_out, int out_size, void* d_ws, size_t ws_size,
                              hipStream_t stream) {
    const int*   idxs = (const int*)  d_in[0];   // (B*S,) int32, B=1
    const float* W    = (const float*)d_in[1];   // (E, N) fp32
    const float* bias = (const float*)d_in[2];   // (E,)  fp32

    f32x4* out = (f32x4*)d_out;

    const int S     = in_sizes[0];   // B=1
    const int halfS = S / 2;
    const int grid  = S * CHUNKS;    // 2048 blocks: one (i, half-row) tile each

    relpos2d_kernel<<<grid, 256, 0, stream>>>(idxs, W, bias, out, S, halfS);
}